// Round 1
// 303.021 us; speedup vs baseline: 1.0739x; 1.0739x over previous
//
#include <hip/hip_runtime.h>
#include <hip/hip_bf16.h>

#define N_NODES 50000
#define N_EDGES 1000000
#define C       128
#define N_REL   8
#define N_SEG   (N_NODES * N_REL)       // 400000
#define KTOT    (N_REL * C + C)         // 1152 = 8 rel chunks + self
#define KC_CNT  (KTOT / 32)             // 36 MFMA k-chunks
#define A_STRIDE 1160                   // 1152 + 8 bf16 pad per row
#define NCHUNK  ((N_SEG + 1023) / 1024) // 391 scan chunks
#define MV_N    (N_SEG + 1 + N_EDGES)   // 1,400,001 ints to relocate
#define NBLK    (N_NODES / 16)          // 3125 layer blocks
#define FE_BLK  ((N_EDGES + 511) / 512) // 1954 fill edge-blocks

typedef __hip_bfloat16  bf16;
typedef __hip_bfloat162 bf162;
typedef __attribute__((ext_vector_type(8))) short short8;
typedef __attribute__((ext_vector_type(4))) float f32x4;
typedef __attribute__((ext_vector_type(2))) float f32x2;

// ---------------------------------------------------------------- weight fragment index
// B-fragment for mfma_f32_16x16x32_bf16: lane = quad*16 + (n&15) holds
// B[k = kc*32 + quad*8 + j][n], j=0..7 contiguous.
__device__ __forceinline__ size_t frag_index(int k, int n) {
    int nt = n >> 4, n15 = n & 15;
    int kc = k >> 5, quad = (k >> 3) & 3, j = k & 7;
    int lane = quad * 16 + n15;
    return ((size_t)(nt * KC_CNT + kc) * 64 + lane) * 8 + j;
}

// ---------------------------------------------------------------- prep: x->bf16 cvt + seg count
// R11 change: the count atomic's RETURN VALUE is the within-segment rank --
// store it (coalesced) so fillB needs no second (ticket) atomic.
#define CVT_BLOCKS ((N_NODES * C / 2) / 256)          // 12500 (exact)
#define CNT_BLOCKS ((N_EDGES + 255) / 256)            // 3907
__global__ void prep_kernel(const float2* __restrict__ xf, unsigned int* __restrict__ xb,
                            const int* __restrict__ dst, const int* __restrict__ et,
                            int* __restrict__ cnt, int* __restrict__ rank) {
    int bid = blockIdx.x;
    if (bid < CVT_BLOCKS) {
        int i = bid * 256 + threadIdx.x;
        float2 v = xf[i];
        union { bf162 h; unsigned int u; } cv;
        cv.h = bf162(__float2bfloat16(v.x), __float2bfloat16(v.y));
        xb[i] = cv.u;
    } else {
        int e = (bid - CVT_BLOCKS) * 256 + threadIdx.x;
        if (e < N_EDGES) rank[e] = atomicAdd(&cnt[dst[e] * N_REL + et[e]], 1);
    }
}

// ---------------------------------------------------------------- scanA: chunk scans + weight repack
// repack1: plain copy (RP_B blocks).  repack2: tiled GEMM W2cat x linW
// (RPT_B blocks of 16x16 output tiles, staged via LDS -> coalesced).
#define RP_B  (KTOT * C / 256)            // 576
#define RPT_B ((KTOT / 16) * (C / 16))    // 72 * 8 = 576
__global__ void scanA_kernel(const int* __restrict__ cnt, int* __restrict__ offs,
                             int* __restrict__ partials,
                             const float* __restrict__ W1, const float* __restrict__ root1,
                             const float* __restrict__ W2, const float* __restrict__ root2,
                             const float* __restrict__ linW,
                             const float* __restrict__ b2, const float* __restrict__ linb,
                             bf16* __restrict__ Bp1, bf16* __restrict__ Bp2,
                             float* __restrict__ b2p) {
    int bid = blockIdx.x;
    int t   = threadIdx.x;
    if (bid < NCHUNK) {
        __shared__ int tot[256];
        int base = bid * 1024 + t * 4;
        int v0 = (base + 0 < N_SEG) ? cnt[base + 0] : 0;
        int v1 = (base + 1 < N_SEG) ? cnt[base + 1] : 0;
        int v2 = (base + 2 < N_SEG) ? cnt[base + 2] : 0;
        int v3 = (base + 3 < N_SEG) ? cnt[base + 3] : 0;
        int tsum = v0 + v1 + v2 + v3;
        tot[t] = tsum;
        __syncthreads();
        for (int d = 1; d < 256; d <<= 1) {
            int x = tot[t];
            int y = (t >= d) ? tot[t - d] : 0;
            __syncthreads();
            tot[t] = x + y;
            __syncthreads();
        }
        int excl = tot[t] - tsum;
        if (base + 0 < N_SEG) offs[base + 0] = excl;
        if (base + 1 < N_SEG) offs[base + 1] = excl + v0;
        if (base + 2 < N_SEG) offs[base + 2] = excl + v0 + v1;
        if (base + 3 < N_SEG) offs[base + 3] = excl + v0 + v1 + v2;
        if (t == 255) partials[bid] = tot[255];
    } else if (bid < NCHUNK + RP_B) {
        int idx = (bid - NCHUNK) * 256 + t;
        int k = idx >> 7, n = idx & 127;
        float val;
        if (k < N_REL * C) val = W1[(size_t)k * C + n];
        else               val = root1[(size_t)(k - N_REL * C) * C + n];
        Bp1[frag_index(k, n)] = __float2bfloat16(val);
    } else if (bid < NCHUNK + RP_B + RPT_B) {
        // ---- tiled repack2: out(k0+ty, n0+tx) = sum_m W2cat[k0+ty][m] * linW[m][n0+tx]
        __shared__ float Wt[16][128];    // 8 KB
        __shared__ float Lt[128][16];    // 8 KB
        int tileid = bid - NCHUNK - RP_B;
        int kt = tileid >> 3;            // 0..71  (k0 = kt*16; 1024 boundary not straddled)
        int n0 = (tileid & 7) * 16;
        int k0 = kt * 16;
        const float* baseW = (k0 < N_REL * C) ? (W2 + (size_t)k0 * C)
                                              : (root2 + (size_t)(k0 - N_REL * C) * C);
#pragma unroll
        for (int r = 0; r < 8; r++) {            // 2048 elems, coalesced
            int idx = t + r * 256;
            Wt[idx >> 7][idx & 127] = baseW[idx];
        }
#pragma unroll
        for (int r = 0; r < 8; r++) {            // 2048 elems: m = idx>>4, n = idx&15
            int idx = t + r * 256;
            Lt[idx >> 4][idx & 15] = linW[(size_t)(idx >> 4) * C + n0 + (idx & 15)];
        }
        __syncthreads();
        int ty = t >> 4, tx = t & 15;
        float acc = 0.f;
#pragma unroll 8
        for (int m = 0; m < 128; m++)
            acc += Wt[ty][m] * Lt[m][tx];
        Bp2[frag_index(k0 + ty, n0 + tx)] = __float2bfloat16(acc);
    } else {
        if (t < 128) {
            float acc = linb[t];
            for (int m = 0; m < C; m++)
                acc += b2[m] * linW[(size_t)m * C + t];
            b2p[t] = acc;
        }
    }
}

// ---------------------------------------------------------------- fillB: offs finalize + edge fill
// R11: per edge = 1 random gather (offs_raw) + 1 random scatter. The ticket
// atomic is replaced by prep's stored rank (coalesced read).
__global__ void fillB_kernel(const int* __restrict__ src, const int* __restrict__ dst,
                             const int* __restrict__ et,
                             const int* __restrict__ offs_raw,   // scanA output
                             const int* __restrict__ partials,
                             int* __restrict__ offs_final,
                             const int* __restrict__ rank,
                             int* __restrict__ srcs_out) {
    __shared__ int s[512];
    int t = threadIdx.x;
    int bid = blockIdx.x;
    s[t] = (t < NCHUNK) ? partials[t] : 0;
    __syncthreads();
    for (int d = 1; d < 512; d <<= 1) {
        int x = s[t];
        int y = (t >= d) ? s[t - d] : 0;
        __syncthreads();
        s[t] = x + y;          // inclusive scan
        __syncthreads();
    }
    if (bid < NCHUNK) {
        int add = (bid == 0) ? 0 : s[bid - 1];
        int base = bid * 1024 + t * 2;
#pragma unroll
        for (int j = 0; j < 2; j++) {
            int idx = base + j;
            if (idx < N_SEG) offs_final[idx] = offs_raw[idx] + add;
        }
        if (bid == 0 && t == 0) offs_final[N_SEG] = N_EDGES;
    } else {
        int e = (bid - NCHUNK) * 512 + t;
        if (e < N_EDGES) {
            int seg = dst[e] * N_REL + et[e];
            int chunk = seg >> 10;
            int base = offs_raw[seg] + ((chunk == 0) ? 0 : s[chunk - 1]);
            srcs_out[base + rank[e]] = src[e];
        }
    }
}

// ---------------------------------------------------------------- fused layer
// Block: 16 nodes, 512 threads (8 waves). Wave w owns local segments
// [16w, 16w+16) (contiguous CSR edge range). 2-stage pipeline with manual
// ping-pong buffers (statically indexed).
// R11: ALL aggregation control state (i, curSeg, segBeg, segEnd, eend, m) is
// forced wave-uniform via readfirstlane on every offsL read, so flush checks,
// tail guards and batch loops compile to SALU (s_cmp/s_cbranch) and gather
// addresses to SGPR-base + lane-offset, instead of v_cmp/exec-mask dances
// (theory for the 60% VALUBusy @ 8% MfmaUtil).
template <int RELU, int OUT_F32, int COPY_CSR>
__global__ __launch_bounds__(512, 6) void fused_layer(
        const unsigned int* __restrict__ featu,  // [N][64] bf16 pairs
        const int*   __restrict__ offs,          // [N_SEG+1]
        const int*   __restrict__ srcs,          // [N_EDGES]
        const short8* __restrict__ Bp,           // fragment-packed bf16 weights
        const float* __restrict__ bias,          // [128] fp32
        void* __restrict__ outp,                 // [N][128] fp32 or bf16
        int* __restrict__ offs2, int* __restrict__ srcs2)   // CSR copy dst
{
    __shared__ __align__(16) unsigned int At[16 * (A_STRIDE / 2)];  // bf16 pairs
    __shared__ int offsL[129];
    const int tid  = threadIdx.x;
    const int lane = tid & 63;
    const int w    = tid >> 6;          // 0..7
    const int v0   = blockIdx.x * 16;

    if (tid < 129) offsL[tid] = offs[v0 * 8 + tid];
    if (tid < 64)  At[(tid >> 2) * (A_STRIDE / 2) + 576 + (tid & 3)] = 0u;  // pad pairs

    // relocate CSR slice (overlapped with gather latency)
    if (COPY_CSR) {
        for (int i = blockIdx.x * 512 + tid; i < MV_N; i += NBLK * 512) {
            if (i < N_SEG + 1) offs2[i] = offs[i];
            else               srcs2[i - (N_SEG + 1)] = srcs[i - (N_SEG + 1)];
        }
    }

    // self rows -> k range [1024..1151]
    for (int q = tid; q < 16 * 64; q += 512) {
        int node = q >> 6, pch = q & 63;
        At[node * (A_STRIDE / 2) + 512 + pch] = featu[(size_t)(v0 + node) * 64 + pch];
    }
    __syncthreads();

    // ---- aggregation over wave-owned contiguous edge range (16 segments)
    {
        const int segLo = w * 16;
        int curSeg = segLo;
        int i      = __builtin_amdgcn_readfirstlane(offsL[segLo]);          // scalar
        int segBeg = i;                                                     // scalar
        int segEnd = __builtin_amdgcn_readfirstlane(offsL[segLo + 1]);      // scalar
        const int eend = __builtin_amdgcn_readfirstlane(offsL[segLo + 16]); // scalar
        f32x2 acc2 = {0.f, 0.f};

        // flush all segments ending exactly at edge index 'upto' (scalar loop)
        auto FLUSH = [&](int upto) {
            while (segEnd == upto) {
                float inv = (segEnd > segBeg) ? 1.0f / (float)(segEnd - segBeg) : 0.0f;
                union { bf162 h; unsigned int u; } cv;
                cv.h = bf162(__float2bfloat16(acc2.x * inv), __float2bfloat16(acc2.y * inv));
                At[(curSeg >> 3) * (A_STRIDE / 2) + (curSeg & 7) * 64 + lane] = cv.u;
                acc2.x = 0.f; acc2.y = 0.f;
                segBeg = segEnd;
                curSeg++;
                segEnd = __builtin_amdgcn_readfirstlane(offsL[curSeg + 1]);
            }
        };
        auto LOADF = [&](unsigned int (&v)[16], int base) {    // base is scalar
            int sv[16];
#pragma unroll
            for (int j = 0; j < 16; j++) sv[j] = srcs[base + j];
#pragma unroll
            for (int j = 0; j < 16; j++) v[j] = featu[(size_t)sv[j] * 64 + lane];
        };
        auto FOLD16 = [&](unsigned int (&v)[16]) {
#pragma unroll
            for (int j = 0; j < 16; j++) {
                FLUSH(i + j);
                union { unsigned int u; float f; } lo, hi;
                lo.u = v[j] << 16;
                hi.u = v[j] & 0xFFFF0000u;
                f32x2 tadd = {lo.f, hi.f};
                acc2 += tadd;
            }
            i += 16;
        };

        unsigned int valsA[16], valsB[16];
        const int nfull = (eend - i) >> 4;          // scalar batch count
        if (nfull > 0) {
            LOADF(valsA, i);
            int b = 0;
            while (true) {                          // uniform control flow
                if (b + 1 < nfull) LOADF(valsB, i + 16);
                FOLD16(valsA);
                b++;
                if (b >= nfull) break;
                if (b + 1 < nfull) LOADF(valsA, i + 16);
                FOLD16(valsB);
                b++;
                if (b >= nfull) break;
            }
        }
        // tail batch (m < 16, scalar m -> uniform branches, no exec masking)
        {
            const int m = eend - i;
            if (m > 0) {
                int sv[16];
#pragma unroll
                for (int j = 0; j < 16; j++) if (j < m) sv[j] = srcs[i + j];
#pragma unroll
                for (int j = 0; j < 16; j++) if (j < m) valsA[j] = featu[(size_t)sv[j] * 64 + lane];
#pragma unroll
                for (int j = 0; j < 16; j++) {
                    if (j < m) {
                        FLUSH(i + j);
                        union { unsigned int u; float f; } lo, hi;
                        lo.u = valsA[j] << 16;
                        hi.u = valsA[j] & 0xFFFF0000u;
                        f32x2 tadd = {lo.f, hi.f};
                        acc2 += tadd;
                    }
                }
            }
        }
        // trailing flushes (last non-empty segment + empty tails)
        while (curSeg < segLo + 16) {
            float inv = (segEnd > segBeg) ? 1.0f / (float)(segEnd - segBeg) : 0.0f;
            union { bf162 h; unsigned int u; } cv;
            cv.h = bf162(__float2bfloat16(acc2.x * inv), __float2bfloat16(acc2.y * inv));
            At[(curSeg >> 3) * (A_STRIDE / 2) + (curSeg & 7) * 64 + lane] = cv.u;
            acc2.x = 0.f; acc2.y = 0.f;
            segBeg = segEnd;
            curSeg++;
            if (curSeg < segLo + 16)
                segEnd = __builtin_amdgcn_readfirstlane(offsL[curSeg + 1]);
        }
    }
    __syncthreads();

    // ---- MFMA GEMM: wave w computes N-tile w (cols 16w..16w+15)
    const int quad = lane >> 4, n15 = lane & 15;
    f32x4 acc = {0.f, 0.f, 0.f, 0.f};
    const short* Ash = (const short*)At;

    short8 b0 = Bp[(size_t)(w * KC_CNT) * 64 + lane];
#pragma unroll 4
    for (int kc = 0; kc < KC_CNT; kc++) {
        short8 cb0 = b0;
        if (kc + 1 < KC_CNT)
            b0 = Bp[(size_t)(w * KC_CNT + kc + 1) * 64 + lane];
        short8 a = *reinterpret_cast<const short8*>(Ash + n15 * A_STRIDE + kc * 32 + quad * 8);
        acc = __builtin_amdgcn_mfma_f32_16x16x32_bf16(a, cb0, acc, 0, 0, 0);
    }

    // epilogue: D[m = quad*4 + r][col = w*16 + n15]
    {
        int col = w * 16 + n15;
        float bv = bias[col];
#pragma unroll
        for (int r = 0; r < 4; r++) {
            int m = quad * 4 + r;
            float v = acc[r] + bv;
            if (RELU) v = fmaxf(v, 0.f);
            if (OUT_F32) ((float*)outp)[(size_t)(v0 + m) * C + col] = v;
            else         ((bf16*)outp)[(size_t)(v0 + m) * C + col] = __float2bfloat16(v);
        }
    }
}

// ---------------------------------------------------------------- launch
// fp32 I/O. ZERO d_ws usage. Provenance:
//   d_out lo   : CSR scratch. offs_final ALIASES cnt (cnt dead after scanA;
//                fillB writes it after scanA completes -- stream ordered).
//   d_out mid  : rank [N_EDGES] (written by prep, read by fillB)
//   d_out hi   : x as bf16 (12.8 MB @ +11,202,048, 256B-ALIGNED) [dead after layer 1]
//   x buffer lo: h1 bf16 (12.8 MB)                            [x fp32 dead after cvt]
//   x buffer hi: packed weights Bp1/Bp2/b2p (@ +13.0 MB)      [written in scanA]
//   ei buffer  : final CSR (offs2+srcs2), copied BY layer 1   [ei dead after fillB]
//   d_out      : final fp32 output (layer 2 writes directly)
extern "C" void kernel_launch(void* const* d_in, const int* in_sizes, int n_in,
                              void* d_out, int out_size, void* d_ws, size_t ws_size,
                              hipStream_t stream) {
    const float* x     = (const float*)d_in[0];
    const int*   ei    = (const int*)d_in[1];
    const int*   et    = (const int*)d_in[2];
    const float* W1    = (const float*)d_in[3];
    const float* root1 = (const float*)d_in[4];
    const float* b1    = (const float*)d_in[5];
    const float* W2    = (const float*)d_in[6];
    const float* root2 = (const float*)d_in[7];
    const float* b2    = (const float*)d_in[8];
    const float* linW  = (const float*)d_in[9];
    const float* linb  = (const float*)d_in[10];
    const int* src = ei;
    const int* dst = ei + N_EDGES;

    // ---- d_out scratch
    char* ob = (char*)d_out;
    int* cnt_i    = (int*)(ob + 0);          // 1,600,000 B (memset)
    int* offs_f   = (int*)(ob + 0);          // [N_SEG+1] -- aliases cnt (dead after scanA)
    int* offs_t   = (int*)(ob + 1600256);    // 1,600,000 B (raw chunk-local scans)
    int* partials = (int*)(ob + 3200256);    // 1,564 B
    int* srcs_t   = (int*)(ob + 3202048);    // 4,000,000 B -> ends 7,202,048
    int* rank     = (int*)(ob + 7202048);    // 4,000,000 B -> ends 11,202,048
    unsigned int* xb16 = (unsigned int*)(ob + 11202048); // 256B-aligned; ends 24,002,048 < 25.6 MB

    // ---- ei buffer: final CSR (written by layer 1's copy slice)
    char* eb = (char*)d_in[1];
    int* offs2 = (int*)(eb + 0);
    int* srcs2 = (int*)(eb + 1600256);       // ends 5,600,256 < 8 MB

    // ---- x buffer: h1 low, weights high
    char* xbuf = (char*)d_in[0];
    unsigned int* h1 = (unsigned int*)xbuf;          // 12.8 MB
    bf16*  Bp1 = (bf16*)(xbuf + 13000192);           // 16B-aligned, 294,912 B
    bf16*  Bp2 = (bf16*)(xbuf + 13295360);           // 294,912 B
    float* b2p = (float*)(xbuf + 13590528);          // 512 B -> ends < 25.6 MB

    float* out = (float*)d_out;

    hipMemsetAsync(cnt_i, 0, 1600000, stream);   // cnt only (ticket eliminated)
    prep_kernel<<<CVT_BLOCKS + CNT_BLOCKS, 256, 0, stream>>>(
        (const float2*)x, xb16, dst, et, cnt_i, rank);
    scanA_kernel<<<NCHUNK + RP_B + RPT_B + 1, 256, 0, stream>>>(
        cnt_i, offs_t, partials, W1, root1, W2, root2, linW, b2, linb,
        Bp1, Bp2, b2p);
    fillB_kernel<<<NCHUNK + FE_BLK, 512, 0, stream>>>(
        src, dst, et, offs_t, partials, offs_f, rank, srcs_t);

    fused_layer<1, 0, 1><<<NBLK, 512, 0, stream>>>(
        xb16, offs_f, srcs_t, (const short8*)Bp1, b1, (void*)h1, offs2, srcs2);
    fused_layer<0, 1, 0><<<NBLK, 512, 0, stream>>>(
        h1, offs2, srcs2, (const short8*)Bp2, b2p, (void*)out, nullptr, nullptr);

    (void)in_sizes; (void)n_in; (void)out_size; (void)d_ws; (void)ws_size;
}